// Round 1
// baseline (3974.622 us; speedup 1.0000x reference)
//
#include <hip/hip_runtime.h>
#include <stdint.h>

// Problem: V=50000, D=256, H=512, B=64, T=512.  out = stack([c_final, h_final]) fp32 [2,64,512]
// Design: 64 persistent WGs (cooperative), each owns 8 hidden units (32 gate cols).
//   W strip [768,32] bf16 lives in LDS in MFMA-fragment order for all 512 steps.
//   h exchanged per step via ping-pong bf16 buffers in ws + device-scope barrier.
//   x-part of GEMM uses precomputed bf16 embedded sequence and runs BEFORE the barrier wait.

#define NWG     64
#define NTHR    256
#define TSTEPS  512
#define BATCH   64
#define EDIM    256
#define HID     512
#define GCOLS   2048

typedef __attribute__((ext_vector_type(8))) short short8;
typedef __attribute__((ext_vector_type(4))) float f32x4;

// ws layout:
//   0    : unsigned cnt
//   128  : unsigned gen          (gen == number of completed barriers)
//   256  : hbuf0 (64*512 ushort = 65536 B)
//   65792: hbuf1
//   131584: xb bf16 [t][b][d] (16.8 MB)  -- only if ws_size permits

__device__ __forceinline__ unsigned short f2bf(float f) {
  unsigned u = __float_as_uint(f);
  unsigned r = (u + 0x7FFFu + ((u >> 16) & 1u)) >> 16;  // RNE
  return (unsigned short)r;
}
__device__ __forceinline__ float sigf(float x) {
  x = fminf(fmaxf(x, -30.0f), 30.0f);
  return 1.0f / (1.0f + __expf(-x));
}
__device__ __forceinline__ float tanh_fast(float x) {
  x = fminf(fmaxf(x, -15.0f), 15.0f);
  float e = __expf(-2.0f * x);
  return (1.0f - e) / (1.0f + e);
}

__global__ void init_ws(unsigned* ws, int nwords) {
  int i = blockIdx.x * 256 + threadIdx.x;
  if (i < nwords) ws[i] = 0u;
}

// one block per (t,b): gather embedding row, convert to bf16, write xb[t][b][:]
__global__ void embed_k(const int* __restrict__ widx, const float* __restrict__ Wemb,
                        unsigned short* __restrict__ xb) {
  int tb = blockIdx.x;                 // t*64 + b
  int t = tb >> 6, b = tb & 63;
  int wi = widx[b * TSTEPS + t];       // word_indices is [B,T]
  const float* src = Wemb + (size_t)wi * EDIM + threadIdx.x * 4;
  float4 v = *(const float4*)src;
  ushort4 o;
  o.x = f2bf(v.x); o.y = f2bf(v.y); o.z = f2bf(v.z); o.w = f2bf(v.w);
  *(ushort4*)(xb + (size_t)tb * EDIM + threadIdx.x * 4) = o;
}

__device__ __forceinline__ void cell_update(const float* g, const float* bl, int u,
                                            int t, int nw, float& c, float& h) {
  float gi = g[u]      + bl[u];
  float gj = g[8 + u]  + bl[8 + u];
  float gf = g[16 + u] + bl[16 + u];
  float go = g[24 + u] + bl[24 + u];
  float cn = sigf(gf + 1.0f) * c + sigf(gi) * tanh_fast(gj);  // FORGET_BIAS=1
  float hn = sigf(go) * tanh_fast(cn);
  if (t < nw) { c = cn; h = hn; }      // static_rnn: copy state through past end
}

__launch_bounds__(NTHR, 1)
__global__ void lstm_persist(const int* __restrict__ num_words,
                             const int* __restrict__ widx,
                             const float* __restrict__ Wemb,
                             const float* __restrict__ Wk,
                             const float* __restrict__ bias,
                             const unsigned short* __restrict__ xb,
                             unsigned short* __restrict__ hb0,
                             unsigned short* __restrict__ hb1,
                             unsigned* cnt, unsigned* gen,
                             float* __restrict__ out,
                             int has_xb)
{
  // B-fragment-ordered W strip: frag q = (ntile*24 + kk)*64 + lane holds 8 bf16:
  //   B[k = kk*32 + (lane>>4)*8 + j][n = ntile*16 + (lane&15)],  n -> gcol = (n>>3)*512 + u0 + (n&7)
  __shared__ alignas(16) short Wlds[24576];      // 48 KB
  __shared__ float gsc[2304];                    // 4 waves * 16 rows * stride 36
  __shared__ float blds[32];

  const int tid = threadIdx.x;
  const int u0  = blockIdx.x * 8;                // this WG's hidden units u0..u0+7

  for (int q = tid; q < 3072; q += NTHR) {
    int lq = q & 63;
    int kkn = q >> 6;                            // 0..47
    int nt = (kkn >= 24) ? 1 : 0;
    int kk = kkn - nt * 24;
    int kbase = kk * 32 + ((lq >> 4) << 3);
    int n = (nt << 4) + (lq & 15);
    int gcol = ((n >> 3) << 9) + u0 + (n & 7);   // gate g -> cols g*512 + unit (i,j,f,o order)
    short8 v;
#pragma unroll
    for (int j = 0; j < 8; ++j)
      v[j] = (short)f2bf(Wk[(size_t)(kbase + j) * GCOLS + gcol]);
    *(short8*)&Wlds[q * 8] = v;
  }
  if (tid < 32) blds[tid] = bias[((tid >> 3) << 9) + u0 + (tid & 7)];

  // MFMA geometry: wave wv owns batches wv*16..+15 (one 16-row M tile), 2 N tiles of 16 cols.
  const int wv   = tid >> 6;
  const int lane = tid & 63;
  const int bb   = wv * 16 + (lane & 15);        // A-row (batch) this lane loads
  const int kq   = (lane >> 4) << 3;             // k sub-offset 0/8/16/24

  // epilogue ownership: thread handles (b1,u1) and (b2,u2); state fp32 in registers
  const int b1 = tid >> 3, u1 = tid & 7;
  const int b2 = b1 + 32,  u2 = u1;
  const int nw1 = num_words[b1], nw2 = num_words[b2];
  float c1 = 0.f, h1 = 0.f, c2 = 0.f, h2 = 0.f;

  __syncthreads();

  unsigned short* hb[2] = {hb0, hb1};

  for (int t = 0; t < TSTEPS; ++t) {
    f32x4 acc0 = {0.f, 0.f, 0.f, 0.f};
    f32x4 acc1 = {0.f, 0.f, 0.f, 0.f};

    // ---- x part (k = 0..255): independent of recurrence, runs before barrier wait ----
    if (has_xb) {
      const unsigned short* xrow = xb + ((size_t)t * BATCH + bb) * EDIM + kq;
#pragma unroll
      for (int kk = 0; kk < 8; ++kk) {
        short8 a  = __builtin_bit_cast(short8, *(const uint4*)(xrow + kk * 32));
        short8 w0 = *(const short8*)&Wlds[((kk)      * 64 + lane) * 8];
        short8 w1 = *(const short8*)&Wlds[((24 + kk) * 64 + lane) * 8];
        acc0 = __builtin_amdgcn_mfma_f32_16x16x32_bf16(a, w0, acc0, 0, 0, 0);
        acc1 = __builtin_amdgcn_mfma_f32_16x16x32_bf16(a, w1, acc1, 0, 0, 0);
      }
    } else {
      int wi = widx[bb * TSTEPS + t];
      const float* erow = Wemb + (size_t)wi * EDIM + kq;
#pragma unroll
      for (int kk = 0; kk < 8; ++kk) {
        float4 f0 = *(const float4*)(erow + kk * 32);
        float4 f1 = *(const float4*)(erow + kk * 32 + 4);
        short8 a;
        a[0] = (short)f2bf(f0.x); a[1] = (short)f2bf(f0.y);
        a[2] = (short)f2bf(f0.z); a[3] = (short)f2bf(f0.w);
        a[4] = (short)f2bf(f1.x); a[5] = (short)f2bf(f1.y);
        a[6] = (short)f2bf(f1.z); a[7] = (short)f2bf(f1.w);
        short8 w0 = *(const short8*)&Wlds[((kk)      * 64 + lane) * 8];
        short8 w1 = *(const short8*)&Wlds[((24 + kk) * 64 + lane) * 8];
        acc0 = __builtin_amdgcn_mfma_f32_16x16x32_bf16(a, w0, acc0, 0, 0, 0);
        acc1 = __builtin_amdgcn_mfma_f32_16x16x32_bf16(a, w1, acc1, 0, 0, 0);
      }
    }

    // ---- wait until barrier t-1 completed (gen >= t); acquire invalidates L1/L2 ----
    if (t > 0) {
      if (tid == 0) {
        while (__hip_atomic_load(gen, __ATOMIC_ACQUIRE, __HIP_MEMORY_SCOPE_AGENT) < (unsigned)t)
          __builtin_amdgcn_s_sleep(1);
      }
      __syncthreads();
    }

    // ---- h part (k = 256..767) reading hbuf[t&1] ----
    const unsigned short* hrow = hb[t & 1] + bb * HID + kq;
#pragma unroll
    for (int kk = 0; kk < 16; ++kk) {
      short8 a  = __builtin_bit_cast(short8, *(const uint4*)(hrow + kk * 32));
      short8 w0 = *(const short8*)&Wlds[((8 + kk)  * 64 + lane) * 8];
      short8 w1 = *(const short8*)&Wlds[((32 + kk) * 64 + lane) * 8];
      acc0 = __builtin_amdgcn_mfma_f32_16x16x32_bf16(a, w0, acc0, 0, 0, 0);
      acc1 = __builtin_amdgcn_mfma_f32_16x16x32_bf16(a, w1, acc1, 0, 0, 0);
    }

    // ---- C/D (col=lane&15, row=(lane>>4)*4+reg) -> LDS for gate regrouping ----
#pragma unroll
    for (int r = 0; r < 4; ++r) {
      int row = ((lane >> 4) << 2) + r;
      gsc[wv * 576 + row * 36 + (lane & 15)]      = acc0[r];
      gsc[wv * 576 + row * 36 + 16 + (lane & 15)] = acc1[r];
    }
    __syncthreads();

    unsigned short* hw = hb[(t + 1) & 1];
    {
      const float* g = &gsc[((b1 >> 4) * 576) + ((b1 & 15) * 36)];
      cell_update(g, blds, u1, t, nw1, c1, h1);
      hw[b1 * HID + u0 + u1] = f2bf(h1);
    }
    {
      const float* g = &gsc[((b2 >> 4) * 576) + ((b2 & 15) * 36)];
      cell_update(g, blds, u2, t, nw2, c2, h2);
      hw[b2 * HID + u0 + u2] = f2bf(h2);
    }

    // ---- arrive: release h writes, last arriver resets cnt then bumps gen ----
    __syncthreads();   // drains this WG's stores (vmcnt 0) into L2
    if (tid == 0) {
      unsigned prev = __hip_atomic_fetch_add(cnt, 1u, __ATOMIC_ACQ_REL, __HIP_MEMORY_SCOPE_AGENT);
      if (prev == NWG - 1) {
        __hip_atomic_store(cnt, 0u, __ATOMIC_RELAXED, __HIP_MEMORY_SCOPE_AGENT);
        __hip_atomic_fetch_add(gen, 1u, __ATOMIC_ACQ_REL, __HIP_MEMORY_SCOPE_AGENT);
      }
    }
  }

  // final state: out[0][b][h]=c, out[1][b][h]=h
  out[b1 * HID + u0 + u1]         = c1;
  out[32768 + b1 * HID + u0 + u1] = h1;
  out[b2 * HID + u0 + u2]         = c2;
  out[32768 + b2 * HID + u0 + u2] = h2;
}

extern "C" void kernel_launch(void* const* d_in, const int* in_sizes, int n_in,
                              void* d_out, int out_size, void* d_ws, size_t ws_size,
                              hipStream_t stream) {
  const int*   widx = (const int*)d_in[0];
  const int*   nw   = (const int*)d_in[1];
  const float* Wemb = (const float*)d_in[2];
  const float* Wk   = (const float*)d_in[3];
  const float* bias = (const float*)d_in[4];
  float* out = (float*)d_out;
  char* ws = (char*)d_ws;

  unsigned* cnt = (unsigned*)ws;
  unsigned* gen = (unsigned*)(ws + 128);
  unsigned short* hb0 = (unsigned short*)(ws + 256);
  unsigned short* hb1 = (unsigned short*)(ws + 65792);
  unsigned short* xb  = (unsigned short*)(ws + 131584);

  size_t need = 131584ull + (size_t)TSTEPS * BATCH * EDIM * 2;
  int has_xb = (ws_size >= need) ? 1 : 0;

  int init_words = (int)(((ws_size < 131328ull ? ws_size : 131328ull)) / 4);
  init_ws<<<129, 256, 0, stream>>>((unsigned*)ws, init_words);
  if (has_xb)
    embed_k<<<TSTEPS * BATCH, 64, 0, stream>>>(widx, Wemb, xb);

  void* args[] = {(void*)&nw, (void*)&widx, (void*)&Wemb, (void*)&Wk, (void*)&bias,
                  (void*)&xb, (void*)&hb0, (void*)&hb1, (void*)&cnt, (void*)&gen,
                  (void*)&out, (void*)&has_xb};
  hipLaunchCooperativeKernel((void*)lstm_persist, dim3(NWG), dim3(NTHR), args, 0, stream);
}

// Round 2
// 3376.390 us; speedup vs baseline: 1.1772x; 1.1772x over previous
//
#include <hip/hip_runtime.h>
#include <stdint.h>

// Problem: V=50000, D=256, H=512, B=64, T=512.  out = stack([c_final, h_final]) fp32 [2,64,512]
// Design: 64 persistent WGs (cooperative), each owns 8 hidden units (32 gate cols).
//   W strip [768,32] bf16 lives in LDS in MFMA-fragment order for all 512 steps.
//   h exchanged per step via ping-pong bf16 buffers in ws.
//   R2: distributed flag barrier (1 flag/WG, own cacheline) + write-through relaxed
//   atomic h stores (no buffer_wbl2) + single acquire buffer_inv per step per WG.

#define NWG     64
#define NTHR    256
#define TSTEPS  512
#define BATCH   64
#define EDIM    256
#define HID     512
#define GCOLS   2048

typedef __attribute__((ext_vector_type(8))) short short8;
typedef __attribute__((ext_vector_type(4))) float f32x4;

// ws layout:
//   0      : (unused, kept zeroed)
//   256    : flags[64], one unsigned per 128 B  (8192 B)
//   8448   : hbuf0 (64*512 ushort = 65536 B)
//   73984  : hbuf1
//   139520 : xb bf16 [t][b][d] (16.8 MB)  -- only if ws_size permits

__device__ __forceinline__ unsigned short f2bf(float f) {
  unsigned u = __float_as_uint(f);
  unsigned r = (u + 0x7FFFu + ((u >> 16) & 1u)) >> 16;  // RNE
  return (unsigned short)r;
}
__device__ __forceinline__ float sigf(float x) {
  x = fminf(fmaxf(x, -30.0f), 30.0f);
  return 1.0f / (1.0f + __expf(-x));
}
__device__ __forceinline__ float tanh_fast(float x) {
  x = fminf(fmaxf(x, -15.0f), 15.0f);
  float e = __expf(-2.0f * x);
  return (1.0f - e) / (1.0f + e);
}

__global__ void init_ws(unsigned* ws, int nwords) {
  int i = blockIdx.x * 256 + threadIdx.x;
  if (i < nwords) ws[i] = 0u;
}

// one block per (t,b): gather embedding row, convert to bf16, write xb[t][b][:]
__global__ void embed_k(const int* __restrict__ widx, const float* __restrict__ Wemb,
                        unsigned short* __restrict__ xb) {
  int tb = blockIdx.x;                 // t*64 + b
  int t = tb >> 6, b = tb & 63;
  int wi = widx[b * TSTEPS + t];       // word_indices is [B,T]
  const float* src = Wemb + (size_t)wi * EDIM + threadIdx.x * 4;
  float4 v = *(const float4*)src;
  ushort4 o;
  o.x = f2bf(v.x); o.y = f2bf(v.y); o.z = f2bf(v.z); o.w = f2bf(v.w);
  *(ushort4*)(xb + (size_t)tb * EDIM + threadIdx.x * 4) = o;
}

__device__ __forceinline__ void cell_update(const float* g, const float* bl, int u,
                                            int t, int nw, float& c, float& h) {
  float gi = g[u]      + bl[u];
  float gj = g[8 + u]  + bl[8 + u];
  float gf = g[16 + u] + bl[16 + u];
  float go = g[24 + u] + bl[24 + u];
  float cn = sigf(gf + 1.0f) * c + sigf(gi) * tanh_fast(gj);  // FORGET_BIAS=1
  float hn = sigf(go) * tanh_fast(cn);
  if (t < nw) { c = cn; h = hn; }      // static_rnn: copy state through past end
}

__launch_bounds__(NTHR, 1)
__global__ void lstm_persist(const int* __restrict__ num_words,
                             const int* __restrict__ widx,
                             const float* __restrict__ Wemb,
                             const float* __restrict__ Wk,
                             const float* __restrict__ bias,
                             const unsigned short* __restrict__ xb,
                             unsigned short* __restrict__ hb0,
                             unsigned short* __restrict__ hb1,
                             unsigned* flags,
                             float* __restrict__ out,
                             int has_xb)
{
  // B-fragment-ordered W strip: frag q = (ntile*24 + kk)*64 + lane holds 8 bf16:
  //   B[k = kk*32 + (lane>>4)*8 + j][n = ntile*16 + (lane&15)],  n -> gcol = (n>>3)*512 + u0 + (n&7)
  __shared__ alignas(16) short Wlds[24576];      // 48 KB
  __shared__ float gsc[2304];                    // 4 waves * 16 rows * stride 36
  __shared__ float blds[32];
  __shared__ alignas(16) unsigned short hst[512]; // h staging [b][u-u0] for packed uint stores

  const int tid = threadIdx.x;
  const int u0  = blockIdx.x * 8;                // this WG's hidden units u0..u0+7

  for (int q = tid; q < 3072; q += NTHR) {
    int lq = q & 63;
    int kkn = q >> 6;                            // 0..47
    int nt = (kkn >= 24) ? 1 : 0;
    int kk = kkn - nt * 24;
    int kbase = kk * 32 + ((lq >> 4) << 3);
    int n = (nt << 4) + (lq & 15);
    int gcol = ((n >> 3) << 9) + u0 + (n & 7);   // gate g -> cols g*512 + unit (i,j,f,o order)
    short8 v;
#pragma unroll
    for (int j = 0; j < 8; ++j)
      v[j] = (short)f2bf(Wk[(size_t)(kbase + j) * GCOLS + gcol]);
    *(short8*)&Wlds[q * 8] = v;
  }
  if (tid < 32) blds[tid] = bias[((tid >> 3) << 9) + u0 + (tid & 7)];

  // MFMA geometry: wave wv owns batches wv*16..+15 (one 16-row M tile), 2 N tiles of 16 cols.
  const int wv   = tid >> 6;
  const int lane = tid & 63;
  const int bb   = wv * 16 + (lane & 15);        // A-row (batch) this lane loads
  const int kq   = (lane >> 4) << 3;             // k sub-offset 0/8/16/24

  // epilogue ownership: thread handles (b1,u1) and (b2,u2); state fp32 in registers
  const int b1 = tid >> 3, u1 = tid & 7;
  const int b2 = b1 + 32,  u2 = u1;
  const int nw1 = num_words[b1], nw2 = num_words[b2];
  float c1 = 0.f, h1 = 0.f, c2 = 0.f, h2 = 0.f;

  __syncthreads();

  unsigned short* hb[2] = {hb0, hb1};

  for (int t = 0; t < TSTEPS; ++t) {
    f32x4 acc0 = {0.f, 0.f, 0.f, 0.f};
    f32x4 acc1 = {0.f, 0.f, 0.f, 0.f};

    // ---- x part (k = 0..255): independent of recurrence, runs before barrier wait ----
    if (has_xb) {
      const unsigned short* xrow = xb + ((size_t)t * BATCH + bb) * EDIM + kq;
#pragma unroll
      for (int kk = 0; kk < 8; ++kk) {
        short8 a  = __builtin_bit_cast(short8, *(const uint4*)(xrow + kk * 32));
        short8 w0 = *(const short8*)&Wlds[((kk)      * 64 + lane) * 8];
        short8 w1 = *(const short8*)&Wlds[((24 + kk) * 64 + lane) * 8];
        acc0 = __builtin_amdgcn_mfma_f32_16x16x32_bf16(a, w0, acc0, 0, 0, 0);
        acc1 = __builtin_amdgcn_mfma_f32_16x16x32_bf16(a, w1, acc1, 0, 0, 0);
      }
    } else {
      int wi = widx[bb * TSTEPS + t];
      const float* erow = Wemb + (size_t)wi * EDIM + kq;
#pragma unroll
      for (int kk = 0; kk < 8; ++kk) {
        float4 f0 = *(const float4*)(erow + kk * 32);
        float4 f1 = *(const float4*)(erow + kk * 32 + 4);
        short8 a;
        a[0] = (short)f2bf(f0.x); a[1] = (short)f2bf(f0.y);
        a[2] = (short)f2bf(f0.z); a[3] = (short)f2bf(f0.w);
        a[4] = (short)f2bf(f1.x); a[5] = (short)f2bf(f1.y);
        a[6] = (short)f2bf(f1.z); a[7] = (short)f2bf(f1.w);
        short8 w0 = *(const short8*)&Wlds[((kk)      * 64 + lane) * 8];
        short8 w1 = *(const short8*)&Wlds[((24 + kk) * 64 + lane) * 8];
        acc0 = __builtin_amdgcn_mfma_f32_16x16x32_bf16(a, w0, acc0, 0, 0, 0);
        acc1 = __builtin_amdgcn_mfma_f32_16x16x32_bf16(a, w1, acc1, 0, 0, 0);
      }
    }

    // ---- wait: all WGs' flags >= t (flag i set to t at end of step t-1) ----
    if (t > 0) {
      if (tid < 64) {   // exactly wave 0, all 64 lanes
        const unsigned tgt = (unsigned)t;
        for (;;) {
          unsigned v = __hip_atomic_load(&flags[tid << 5], __ATOMIC_RELAXED,
                                         __HIP_MEMORY_SCOPE_AGENT);
          if (__ballot(v >= tgt) == 0xFFFFFFFFFFFFFFFFull) break;
          __builtin_amdgcn_s_sleep(1);
        }
        // one acquire load -> waitcnt + buffer_inv (L1+L2), publishes h to plain loads
        (void)__hip_atomic_load(&flags[tid << 5], __ATOMIC_ACQUIRE,
                                __HIP_MEMORY_SCOPE_AGENT);
      }
      __syncthreads();
    }

    // ---- h part (k = 256..767) reading hbuf[t&1] with plain (L2-cached) loads ----
    const unsigned short* hrow = hb[t & 1] + bb * HID + kq;
#pragma unroll
    for (int kk = 0; kk < 16; ++kk) {
      short8 a  = __builtin_bit_cast(short8, *(const uint4*)(hrow + kk * 32));
      short8 w0 = *(const short8*)&Wlds[((8 + kk)  * 64 + lane) * 8];
      short8 w1 = *(const short8*)&Wlds[((32 + kk) * 64 + lane) * 8];
      acc0 = __builtin_amdgcn_mfma_f32_16x16x32_bf16(a, w0, acc0, 0, 0, 0);
      acc1 = __builtin_amdgcn_mfma_f32_16x16x32_bf16(a, w1, acc1, 0, 0, 0);
    }

    // ---- C/D (col=lane&15, row=(lane>>4)*4+reg) -> LDS for gate regrouping ----
#pragma unroll
    for (int r = 0; r < 4; ++r) {
      int row = ((lane >> 4) << 2) + r;
      gsc[wv * 576 + row * 36 + (lane & 15)]      = acc0[r];
      gsc[wv * 576 + row * 36 + 16 + (lane & 15)] = acc1[r];
    }
    __syncthreads();

    // ---- epilogue: cell update; stage new h (bf16) into LDS ----
    {
      const float* g = &gsc[((b1 >> 4) * 576) + ((b1 & 15) * 36)];
      cell_update(g, blds, u1, t, nw1, c1, h1);
      hst[(b1 << 3) + u1] = f2bf(h1);
    }
    {
      const float* g = &gsc[((b2 >> 4) * 576) + ((b2 & 15) * 36)];
      cell_update(g, blds, u2, t, nw2, c2, h2);
      hst[(b2 << 3) + u2] = f2bf(h2);
    }

    // ---- arrive: write-through h (relaxed agent atomics), drain, set own flag ----
    if (t + 1 < TSTEPS) {
      unsigned short* hw = hb[(t + 1) & 1];
      __syncthreads();                           // hst complete
      {
        int bs = tid >> 2, p = tid & 3;          // 256 threads x 1 uint = 1 KB
        unsigned v = *(const unsigned*)&hst[(bs << 3) + (p << 1)];
        __hip_atomic_store((unsigned*)(hw + (size_t)bs * HID + u0) + p, v,
                           __ATOMIC_RELAXED, __HIP_MEMORY_SCOPE_AGENT);
      }
      asm volatile("s_waitcnt vmcnt(0)" ::: "memory");
      __syncthreads();                           // all waves drained
      if (tid == 0)
        __hip_atomic_store(&flags[(unsigned)blockIdx.x << 5], (unsigned)(t + 1),
                           __ATOMIC_RELAXED, __HIP_MEMORY_SCOPE_AGENT);
    }
  }

  // final state: out[0][b][h]=c, out[1][b][h]=h
  out[b1 * HID + u0 + u1]         = c1;
  out[32768 + b1 * HID + u0 + u1] = h1;
  out[b2 * HID + u0 + u2]         = c2;
  out[32768 + b2 * HID + u0 + u2] = h2;
}

extern "C" void kernel_launch(void* const* d_in, const int* in_sizes, int n_in,
                              void* d_out, int out_size, void* d_ws, size_t ws_size,
                              hipStream_t stream) {
  const int*   widx = (const int*)d_in[0];
  const int*   nw   = (const int*)d_in[1];
  const float* Wemb = (const float*)d_in[2];
  const float* Wk   = (const float*)d_in[3];
  const float* bias = (const float*)d_in[4];
  float* out = (float*)d_out;
  char* ws = (char*)d_ws;

  unsigned* flags = (unsigned*)(ws + 256);
  unsigned short* hb0 = (unsigned short*)(ws + 8448);
  unsigned short* hb1 = (unsigned short*)(ws + 73984);
  unsigned short* xb  = (unsigned short*)(ws + 139520);

  size_t need = 139520ull + (size_t)TSTEPS * BATCH * EDIM * 2;
  int has_xb = (ws_size >= need) ? 1 : 0;

  size_t init_bytes = ws_size < 139520ull ? ws_size : 139520ull;
  int init_words = (int)(init_bytes / 4);
  init_ws<<<(init_words + 255) / 256, 256, 0, stream>>>((unsigned*)ws, init_words);
  if (has_xb)
    embed_k<<<TSTEPS * BATCH, 64, 0, stream>>>(widx, Wemb, xb);

  void* args[] = {(void*)&nw, (void*)&widx, (void*)&Wemb, (void*)&Wk, (void*)&bias,
                  (void*)&xb, (void*)&hb0, (void*)&hb1, (void*)&flags,
                  (void*)&out, (void*)&has_xb};
  hipLaunchCooperativeKernel((void*)lstm_persist, dim3(NWG), dim3(NTHR), args, 0, stream);
}

// Round 3
// 2819.419 us; speedup vs baseline: 1.4097x; 1.1975x over previous
//
#include <hip/hip_runtime.h>
#include <stdint.h>

// Problem: V=50000, D=256, H=512, B=64, T=512.  out = stack([c_final, h_final]) fp32 [2,64,512]
// Design: 64 persistent WGs (cooperative), each owns 8 hidden units (32 gate cols).
//   W strip [768,32] bf16 lives in LDS in MFMA-fragment order for all 512 steps.
//   h exchanged per step via ping-pong bf16 buffers in ws.
//   R3: NO cache maintenance (no buffer_inv / wbl2). All cross-WG data (h, flags)
//   moves via sc0 sc1 (system-coherent, L1+L2-bypass) loads/stores straight to the
//   LLC coherence point. L2 stays warm for xb/W. Distributed per-WG flags.

#define NWG     64
#define NTHR    256
#define TSTEPS  512
#define BATCH   64
#define EDIM    256
#define HID     512
#define GCOLS   2048

typedef __attribute__((ext_vector_type(8))) short short8;
typedef __attribute__((ext_vector_type(4))) float f32x4;

// ws layout:
//   256    : flags[64], one unsigned per 128 B  (8192 B)
//   8448   : hbuf0 (64*512 ushort = 65536 B)
//   73984  : hbuf1
//   139520 : xb bf16 [t][b][d] (16.8 MB)  -- only if ws_size permits

__device__ __forceinline__ unsigned short f2bf(float f) {
  unsigned u = __float_as_uint(f);
  unsigned r = (u + 0x7FFFu + ((u >> 16) & 1u)) >> 16;  // RNE
  return (unsigned short)r;
}
__device__ __forceinline__ float sigf(float x) {
  x = fminf(fmaxf(x, -30.0f), 30.0f);
  return 1.0f / (1.0f + __expf(-x));
}
__device__ __forceinline__ float tanh_fast(float x) {
  x = fminf(fmaxf(x, -15.0f), 15.0f);
  float e = __expf(-2.0f * x);
  return (1.0f - e) / (1.0f + e);
}

__global__ void init_ws(unsigned* ws, int nwords) {
  int i = blockIdx.x * 256 + threadIdx.x;
  if (i < nwords) ws[i] = 0u;
}

// one block per (t,b): gather embedding row, convert to bf16, write xb[t][b][:]
__global__ void embed_k(const int* __restrict__ widx, const float* __restrict__ Wemb,
                        unsigned short* __restrict__ xb) {
  int tb = blockIdx.x;                 // t*64 + b
  int t = tb >> 6, b = tb & 63;
  int wi = widx[b * TSTEPS + t];       // word_indices is [B,T]
  const float* src = Wemb + (size_t)wi * EDIM + threadIdx.x * 4;
  float4 v = *(const float4*)src;
  ushort4 o;
  o.x = f2bf(v.x); o.y = f2bf(v.y); o.z = f2bf(v.z); o.w = f2bf(v.w);
  *(ushort4*)(xb + (size_t)tb * EDIM + threadIdx.x * 4) = o;
}

__device__ __forceinline__ void cell_update(const float* g, const float* bl, int u,
                                            int t, int nw, float& c, float& h) {
  float gi = g[u]      + bl[u];
  float gj = g[8 + u]  + bl[8 + u];
  float gf = g[16 + u] + bl[16 + u];
  float go = g[24 + u] + bl[24 + u];
  float cn = sigf(gf + 1.0f) * c + sigf(gi) * tanh_fast(gj);  // FORGET_BIAS=1
  float hn = sigf(go) * tanh_fast(cn);
  if (t < nw) { c = cn; h = hn; }      // static_rnn: copy state through past end
}

__launch_bounds__(NTHR, 1)
__global__ void lstm_persist(const int* __restrict__ num_words,
                             const int* __restrict__ widx,
                             const float* __restrict__ Wemb,
                             const float* __restrict__ Wk,
                             const float* __restrict__ bias,
                             const unsigned short* __restrict__ xb,
                             unsigned short* __restrict__ hb0,
                             unsigned short* __restrict__ hb1,
                             unsigned* flags,
                             float* __restrict__ out,
                             int has_xb)
{
  // B-fragment-ordered W strip: frag q = (ntile*24 + kk)*64 + lane holds 8 bf16:
  //   B[k = kk*32 + (lane>>4)*8 + j][n = ntile*16 + (lane&15)],  n -> gcol = (n>>3)*512 + u0 + (n&7)
  __shared__ alignas(16) short Wlds[24576];      // 48 KB
  __shared__ float gsc[2304];                    // 4 waves * 16 rows * stride 36
  __shared__ float blds[32];
  __shared__ alignas(16) unsigned short hst[512]; // h staging [b][u-u0]

  const int tid = threadIdx.x;
  const int u0  = blockIdx.x * 8;                // this WG's hidden units u0..u0+7

  for (int q = tid; q < 3072; q += NTHR) {
    int lq = q & 63;
    int kkn = q >> 6;                            // 0..47
    int nt = (kkn >= 24) ? 1 : 0;
    int kk = kkn - nt * 24;
    int kbase = kk * 32 + ((lq >> 4) << 3);
    int n = (nt << 4) + (lq & 15);
    int gcol = ((n >> 3) << 9) + u0 + (n & 7);   // gate g -> cols g*512 + unit (i,j,f,o order)
    short8 v;
#pragma unroll
    for (int j = 0; j < 8; ++j)
      v[j] = (short)f2bf(Wk[(size_t)(kbase + j) * GCOLS + gcol]);
    *(short8*)&Wlds[q * 8] = v;
  }
  if (tid < 32) blds[tid] = bias[((tid >> 3) << 9) + u0 + (tid & 7)];

  // MFMA geometry: wave wv owns batches wv*16..+15 (one 16-row M tile), 2 N tiles of 16 cols.
  const int wv   = tid >> 6;
  const int lane = tid & 63;
  const int bb   = wv * 16 + (lane & 15);        // A-row (batch) this lane loads
  const int kq   = (lane >> 4) << 3;             // k sub-offset 0/8/16/24

  // epilogue ownership: thread handles (b1,u1) and (b2,u2); state fp32 in registers
  const int b1 = tid >> 3, u1 = tid & 7;
  const int b2 = b1 + 32,  u2 = u1;
  const int nw1 = num_words[b1], nw2 = num_words[b2];
  float c1 = 0.f, h1 = 0.f, c2 = 0.f, h2 = 0.f;

  __syncthreads();

  unsigned short* hb[2] = {hb0, hb1};

  for (int t = 0; t < TSTEPS; ++t) {
    f32x4 acc0 = {0.f, 0.f, 0.f, 0.f};
    f32x4 acc1 = {0.f, 0.f, 0.f, 0.f};

    // ---- x part (k = 0..255): independent of recurrence, runs before barrier wait ----
    if (has_xb) {
      const unsigned short* xrow = xb + ((size_t)t * BATCH + bb) * EDIM + kq;
#pragma unroll
      for (int kk = 0; kk < 8; ++kk) {
        short8 a  = __builtin_bit_cast(short8, *(const uint4*)(xrow + kk * 32));
        short8 w0 = *(const short8*)&Wlds[((kk)      * 64 + lane) * 8];
        short8 w1 = *(const short8*)&Wlds[((24 + kk) * 64 + lane) * 8];
        acc0 = __builtin_amdgcn_mfma_f32_16x16x32_bf16(a, w0, acc0, 0, 0, 0);
        acc1 = __builtin_amdgcn_mfma_f32_16x16x32_bf16(a, w1, acc1, 0, 0, 0);
      }
    } else {
      int wi = widx[bb * TSTEPS + t];
      const float* erow = Wemb + (size_t)wi * EDIM + kq;
#pragma unroll
      for (int kk = 0; kk < 8; ++kk) {
        float4 f0 = *(const float4*)(erow + kk * 32);
        float4 f1 = *(const float4*)(erow + kk * 32 + 4);
        short8 a;
        a[0] = (short)f2bf(f0.x); a[1] = (short)f2bf(f0.y);
        a[2] = (short)f2bf(f0.z); a[3] = (short)f2bf(f0.w);
        a[4] = (short)f2bf(f1.x); a[5] = (short)f2bf(f1.y);
        a[6] = (short)f2bf(f1.z); a[7] = (short)f2bf(f1.w);
        short8 w0 = *(const short8*)&Wlds[((kk)      * 64 + lane) * 8];
        short8 w1 = *(const short8*)&Wlds[((24 + kk) * 64 + lane) * 8];
        acc0 = __builtin_amdgcn_mfma_f32_16x16x32_bf16(a, w0, acc0, 0, 0, 0);
        acc1 = __builtin_amdgcn_mfma_f32_16x16x32_bf16(a, w1, acc1, 0, 0, 0);
      }
    }

    // ---- wait: all WGs' flags >= t, via LLC-coherent poll loads (no cache inv) ----
    if (t > 0) {
      if (tid < 64) {   // exactly wave 0, all 64 lanes; lane i polls flag i
        const unsigned* fp = flags + (tid << 5);
        const unsigned tgt = (unsigned)t;
        for (;;) {
          unsigned v;
          asm volatile("global_load_dword %0, %1, off sc0 sc1\n\t"
                       "s_waitcnt vmcnt(0)"
                       : "=v"(v) : "v"(fp));
          if (__ballot(v >= tgt) == 0xFFFFFFFFFFFFFFFFull) break;
        }
      }
      __syncthreads();
    }

    // ---- h part (k = 256..767): batched LLC-coherent loads, one drain, then MFMAs ----
    {
      const unsigned short* hrow = hb[t & 1] + bb * HID + kq;
      uint4 af[16];
#pragma unroll
      for (int kk = 0; kk < 16; ++kk)
        asm volatile("global_load_dwordx4 %0, %1, off sc0 sc1"
                     : "=v"(af[kk]) : "v"(hrow + kk * 32));
      asm volatile("s_waitcnt vmcnt(0)" ::: "memory");
#pragma unroll
      for (int kk = 0; kk < 16; ++kk) {
        short8 a  = __builtin_bit_cast(short8, af[kk]);
        short8 w0 = *(const short8*)&Wlds[((8 + kk)  * 64 + lane) * 8];
        short8 w1 = *(const short8*)&Wlds[((32 + kk) * 64 + lane) * 8];
        acc0 = __builtin_amdgcn_mfma_f32_16x16x32_bf16(a, w0, acc0, 0, 0, 0);
        acc1 = __builtin_amdgcn_mfma_f32_16x16x32_bf16(a, w1, acc1, 0, 0, 0);
      }
    }

    // ---- C/D (col=lane&15, row=(lane>>4)*4+reg) -> LDS for gate regrouping ----
#pragma unroll
    for (int r = 0; r < 4; ++r) {
      int row = ((lane >> 4) << 2) + r;
      gsc[wv * 576 + row * 36 + (lane & 15)]      = acc0[r];
      gsc[wv * 576 + row * 36 + 16 + (lane & 15)] = acc1[r];
    }
    __syncthreads();

    // ---- epilogue: cell update; stage new h (bf16) into LDS ----
    {
      const float* g = &gsc[((b1 >> 4) * 576) + ((b1 & 15) * 36)];
      cell_update(g, blds, u1, t, nw1, c1, h1);
      hst[(b1 << 3) + u1] = f2bf(h1);
    }
    {
      const float* g = &gsc[((b2 >> 4) * 576) + ((b2 & 15) * 36)];
      cell_update(g, blds, u2, t, nw2, c2, h2);
      hst[(b2 << 3) + u2] = f2bf(h2);
    }

    // ---- arrive: write-through h to LLC, drain, set own flag (all sc0 sc1) ----
    if (t + 1 < TSTEPS) {
      unsigned short* hw = hb[(t + 1) & 1];
      __syncthreads();                           // hst complete
      {
        int bs = tid >> 2, p = tid & 3;          // 256 threads x 1 uint = 1 KB
        unsigned v = *(const unsigned*)&hst[(bs << 3) + (p << 1)];
        unsigned* dst = (unsigned*)(hw + (size_t)bs * HID + u0) + p;
        asm volatile("global_store_dword %0, %1, off sc0 sc1"
                     :: "v"(dst), "v"(v) : "memory");
      }
      asm volatile("s_waitcnt vmcnt(0)" ::: "memory");
      __syncthreads();                           // all waves drained
      if (tid == 0) {
        unsigned* fa = flags + ((unsigned)blockIdx.x << 5);
        unsigned fv = (unsigned)(t + 1);
        asm volatile("global_store_dword %0, %1, off sc0 sc1"
                     :: "v"(fa), "v"(fv) : "memory");
      }
    }
  }

  // final state: out[0][b][h]=c, out[1][b][h]=h
  out[b1 * HID + u0 + u1]         = c1;
  out[32768 + b1 * HID + u0 + u1] = h1;
  out[b2 * HID + u0 + u2]         = c2;
  out[32768 + b2 * HID + u0 + u2] = h2;
}

extern "C" void kernel_launch(void* const* d_in, const int* in_sizes, int n_in,
                              void* d_out, int out_size, void* d_ws, size_t ws_size,
                              hipStream_t stream) {
  const int*   widx = (const int*)d_in[0];
  const int*   nw   = (const int*)d_in[1];
  const float* Wemb = (const float*)d_in[2];
  const float* Wk   = (const float*)d_in[3];
  const float* bias = (const float*)d_in[4];
  float* out = (float*)d_out;
  char* ws = (char*)d_ws;

  unsigned* flags = (unsigned*)(ws + 256);
  unsigned short* hb0 = (unsigned short*)(ws + 8448);
  unsigned short* hb1 = (unsigned short*)(ws + 73984);
  unsigned short* xb  = (unsigned short*)(ws + 139520);

  size_t need = 139520ull + (size_t)TSTEPS * BATCH * EDIM * 2;
  int has_xb = (ws_size >= need) ? 1 : 0;

  size_t init_bytes = ws_size < 139520ull ? ws_size : 139520ull;
  int init_words = (int)(init_bytes / 4);
  init_ws<<<(init_words + 255) / 256, 256, 0, stream>>>((unsigned*)ws, init_words);
  if (has_xb)
    embed_k<<<TSTEPS * BATCH, 64, 0, stream>>>(widx, Wemb, xb);

  void* args[] = {(void*)&nw, (void*)&widx, (void*)&Wemb, (void*)&Wk, (void*)&bias,
                  (void*)&xb, (void*)&hb0, (void*)&hb1, (void*)&flags,
                  (void*)&out, (void*)&has_xb};
  hipLaunchCooperativeKernel((void*)lstm_persist, dim3(NWG), dim3(NTHR), args, 0, stream);
}